// Round 1
// baseline (258.972 us; speedup 1.0000x reference)
//
#include <hip/hip_runtime.h>
#include <math.h>

#define Bb 16
#define Tt 28
#define Nn 2048
#define Hh 32
#define LAGS 8
#define LN_EPS 1e-5f

#define TN 32      // n rows per attention block
#define MC 64      // m chunk
#define KPAD 36    // K/V LDS row pad (16B aligned, bank-spread 4g+k)
#define APAD 68    // adj LDS row pad (16B aligned, <=2-way conflicts)

// ---------------- Kernel 1: delayed signal ----------------
// ds[b,n] = sum_tau softmax(delay_logits)[tau] * x[b, T-1-tau, n]
__global__ void k_delayed(const float* __restrict__ x,
                          const float* __restrict__ dlog,
                          float* __restrict__ ds) {
    int idx = blockIdx.x * blockDim.x + threadIdx.x; // over B*N
    float w[LAGS];
    float m = -1e30f;
    #pragma unroll
    for (int t = 0; t < LAGS; ++t) m = fmaxf(m, dlog[t]);
    float s = 0.f;
    #pragma unroll
    for (int t = 0; t < LAGS; ++t) { w[t] = __expf(dlog[t] - m); s += w[t]; }
    float inv = 1.f / s;
    if (idx >= Bb * Nn) return;
    int b = idx / Nn, n = idx % Nn;
    float acc = 0.f;
    #pragma unroll
    for (int t = 0; t < LAGS; ++t)
        acc += (w[t] * inv) * x[(size_t)b * Tt * Nn + (size_t)(Tt - 1 - t) * Nn + n];
    ds[idx] = acc;
}

// ---------------- Kernel 2: fused QKV projection ----------------
// 8 rows per 256-thread block; lane h computes Q/K/V[row][h]
__global__ void k_qkv(const float* __restrict__ feat,
                      const float* __restrict__ Wq, const float* __restrict__ bq,
                      const float* __restrict__ Wk, const float* __restrict__ bk,
                      const float* __restrict__ Wv, const float* __restrict__ bv,
                      float* __restrict__ Q, float* __restrict__ K, float* __restrict__ V) {
    __shared__ float WqT[Hh][Hh + 1], WkT[Hh][Hh + 1], WvT[Hh][Hh + 1];
    __shared__ float f[8][Hh];
    int tid = threadIdx.x;
    for (int i = tid; i < Hh * Hh; i += 256) {
        int h = i >> 5, k = i & 31;
        WqT[k][h] = Wq[i];
        WkT[k][h] = Wk[i];
        WvT[k][h] = Wv[i];
    }
    int row0 = blockIdx.x * 8;
    f[tid >> 5][tid & 31] = feat[(size_t)row0 * Hh + tid];
    __syncthreads();
    int lr = tid >> 5, h = tid & 31;
    float aq = bq[h], ak = bk[h], av = bv[h];
    #pragma unroll
    for (int k = 0; k < Hh; ++k) {
        float fv = f[lr][k];
        aq += fv * WqT[k][h];
        ak += fv * WkT[k][h];
        av += fv * WvT[k][h];
    }
    size_t o = (size_t)row0 * Hh + (size_t)lr * Hh + h;
    Q[o] = aq; K[o] = ak; V[o] = av;
}

// ---------------- Kernel 3: attention (online softmax, flash-style) ------
// block: 256 threads -> 32 n-rows, 8 lanes per row (g). grid: (N/TN, B)
__global__ __launch_bounds__(256)
void k_attn(const float* __restrict__ Q, const float* __restrict__ K,
            const float* __restrict__ V, const float* __restrict__ ds,
            const float* __restrict__ adj, const float* __restrict__ geo_w,
            const float* __restrict__ feat, float* __restrict__ comb) {
    __shared__ float Kl[MC][KPAD];
    __shared__ float Vl[MC][KPAD];
    __shared__ float Al[TN][APAD];
    __shared__ float Dl[MC];
    int b = blockIdx.y;
    int n0 = blockIdx.x * TN;
    int tid = threadIdx.x;
    int nl = tid >> 3;   // 0..31 (row within tile)
    int g  = tid & 7;    // 0..7  (lane group within row)
    int n = n0 + nl;
    float geo = 1.f / (1.f + __expf(-geo_w[0]));
    float cs_q = (1.f - geo) * 0.17677669529663687f; // (1-geo)/sqrt(32)
    float cg   = geo * 5.f;

    // Q row into registers (replicated across the 8 g-lanes)
    float q[Hh];
    const float* qp = Q + ((size_t)b * Nn + n) * Hh;
    #pragma unroll
    for (int k = 0; k < Hh; ++k) q[k] = qp[k];

    float M = -INFINITY, S = 0.f;
    float acc[Hh];
    #pragma unroll
    for (int h = 0; h < Hh; ++h) acc[h] = 0.f;
    float accp = 0.f;

    const float* Kb  = K  + (size_t)b * Nn * Hh;
    const float* Vb  = V  + (size_t)b * Nn * Hh;
    const float* dsb = ds + (size_t)b * Nn;

    for (int m0 = 0; m0 < Nn; m0 += MC) {
        __syncthreads();
        // stage K,V chunk (MC*H = 2048 floats each) via float4
        #pragma unroll
        for (int i = 0; i < 2; ++i) {
            int idx = (tid + i * 256) * 4;     // 0..2044 step 4
            int mm = idx >> 5, kk = idx & 31;
            float4 kv = *(const float4*)(Kb + (size_t)m0 * Hh + idx);
            float4 vv = *(const float4*)(Vb + (size_t)m0 * Hh + idx);
            *(float4*)&Kl[mm][kk] = kv;
            *(float4*)&Vl[mm][kk] = vv;
        }
        // stage adj tile TN x MC via float4
        #pragma unroll
        for (int i = 0; i < 2; ++i) {
            int idx = (tid + i * 256) * 4;
            int r = idx >> 6, c = idx & 63;
            float4 av = *(const float4*)(adj + (size_t)(n0 + r) * Nn + m0 + c);
            *(float4*)&Al[r][c] = av;
        }
        if (tid < MC) Dl[tid] = dsb[m0 + tid];
        __syncthreads();

        // scores for 8 m's per thread: m = g + 8j
        float s[8];
        #pragma unroll
        for (int j = 0; j < 8; ++j) {
            int m = g + 8 * j;
            float a = 0.f;
            #pragma unroll
            for (int k = 0; k < Hh; ++k) a += q[k] * Kl[m][k];
            s[j] = cs_q * a + cg * Al[nl][m];
        }
        // row-chunk max across the 8-lane group
        float lm = s[0];
        #pragma unroll
        for (int j = 1; j < 8; ++j) lm = fmaxf(lm, s[j]);
        lm = fmaxf(lm, __shfl_xor(lm, 1));
        lm = fmaxf(lm, __shfl_xor(lm, 2));
        lm = fmaxf(lm, __shfl_xor(lm, 4));
        float newM = fmaxf(M, lm);
        float r = __expf(M - newM);
        float p[8], psum = 0.f;
        #pragma unroll
        for (int j = 0; j < 8; ++j) { p[j] = __expf(s[j] - newM); psum += p[j]; }
        psum += __shfl_xor(psum, 1);
        psum += __shfl_xor(psum, 2);
        psum += __shfl_xor(psum, 4);
        S = S * r + psum;
        M = newM;
        // rescale + accumulate (per-thread partials over its 8 m's)
        #pragma unroll
        for (int h = 0; h < Hh; ++h) acc[h] *= r;
        accp *= r;
        #pragma unroll
        for (int j = 0; j < 8; ++j) {
            int m = g + 8 * j;
            float pj = p[j];
            #pragma unroll
            for (int h = 0; h < Hh; ++h) acc[h] += pj * Vl[m][h];
            accp += pj * Dl[m];
        }
    }
    // reduce partial accumulators across the 8 g-lanes
    #pragma unroll
    for (int h = 0; h < Hh; ++h) {
        acc[h] += __shfl_xor(acc[h], 1);
        acc[h] += __shfl_xor(acc[h], 2);
        acc[h] += __shfl_xor(acc[h], 4);
    }
    accp += __shfl_xor(accp, 1);
    accp += __shfl_xor(accp, 2);
    accp += __shfl_xor(accp, 4);
    float invS = 1.f / S;
    size_t o = ((size_t)b * Nn + n) * Hh;
    #pragma unroll
    for (int j = 0; j < 4; ++j) {
        int h = g * 4 + j;
        comb[o + h] = feat[o + h] + acc[h] * invS + 0.1f * accp * invS;
    }
}

// ---------------- Kernel 4: output projection + LayerNorm ----------------
__global__ void k_projln(const float* __restrict__ comb,
                         const float* __restrict__ Wo, const float* __restrict__ bo,
                         const float* __restrict__ gamma, const float* __restrict__ beta,
                         float* __restrict__ out) {
    __shared__ float WoT[Hh][Hh + 1];
    __shared__ float f[8][Hh];
    int tid = threadIdx.x;
    for (int i = tid; i < Hh * Hh; i += 256) {
        WoT[i & 31][i >> 5] = Wo[i];
    }
    int row0 = blockIdx.x * 8;
    f[tid >> 5][tid & 31] = comb[(size_t)row0 * Hh + tid];
    __syncthreads();
    int lr = tid >> 5, h = tid & 31;
    float a = bo[h];
    #pragma unroll
    for (int k = 0; k < Hh; ++k) a += f[lr][k] * WoT[k][h];
    // LayerNorm across the 32 lanes of this row
    float mu = a;
    #pragma unroll
    for (int w = 1; w < 32; w <<= 1) mu += __shfl_xor(mu, w);
    mu *= (1.f / 32.f);
    float d = a - mu;
    float v = d * d;
    #pragma unroll
    for (int w = 1; w < 32; w <<= 1) v += __shfl_xor(v, w);
    v *= (1.f / 32.f);
    out[(size_t)row0 * Hh + tid] = d * rsqrtf(v + LN_EPS) * gamma[h] + beta[h];
}

extern "C" void kernel_launch(void* const* d_in, const int* in_sizes, int n_in,
                              void* d_out, int out_size, void* d_ws, size_t ws_size,
                              hipStream_t stream) {
    const float* x     = (const float*)d_in[0];
    const float* feat  = (const float*)d_in[1];
    const float* dlog  = (const float*)d_in[2];
    const float* Wq    = (const float*)d_in[3];
    const float* bq    = (const float*)d_in[4];
    const float* Wk    = (const float*)d_in[5];
    const float* bk    = (const float*)d_in[6];
    const float* Wv    = (const float*)d_in[7];
    const float* bv    = (const float*)d_in[8];
    const float* adj   = (const float*)d_in[9];
    const float* geo   = (const float*)d_in[10];
    const float* Wo    = (const float*)d_in[11];
    const float* bo    = (const float*)d_in[12];
    const float* gamma = (const float*)d_in[13];
    const float* beta  = (const float*)d_in[14];
    float* out = (float*)d_out;

    float* ws  = (float*)d_ws;
    float* Q    = ws;
    float* K    = Q   + (size_t)Bb * Nn * Hh;
    float* V    = K   + (size_t)Bb * Nn * Hh;
    float* dsg  = V   + (size_t)Bb * Nn * Hh;
    float* comb = dsg + (size_t)Bb * Nn;

    k_delayed<<<(Bb * Nn + 255) / 256, 256, 0, stream>>>(x, dlog, dsg);
    k_qkv<<<Bb * Nn / 8, 256, 0, stream>>>(feat, Wq, bq, Wk, bk, Wv, bv, Q, K, V);
    dim3 g2(Nn / TN, Bb);
    k_attn<<<g2, 256, 0, stream>>>(Q, K, V, dsg, adj, geo, feat, comb);
    k_projln<<<Bb * Nn / 8, 256, 0, stream>>>(comb, Wo, bo, gamma, beta, out);
}

// Round 4
// 89.363 us; speedup vs baseline: 2.8980x; 2.8980x over previous
//
#include <hip/hip_runtime.h>
#include <math.h>
#include <stdint.h>

#define Bb 16
#define Tt 28
#define Nn 2048
#define Hh 32
#define LAGS 8
#define LN_EPS 1e-5f

#define KSTR 40    // Kl row stride (shorts): 32 + 8 pad -> 4-way max on reads
#define VSTR 136   // Vl row stride: 128 + 8 pad -> 2-way on reads
#define PSTR 136   // Pt row stride

typedef float f4 __attribute__((ext_vector_type(4)));
typedef short s8v __attribute__((ext_vector_type(8)));
typedef unsigned short u16x8 __attribute__((ext_vector_type(8)));

__device__ __forceinline__ unsigned short f2b(float f) {
    unsigned u = __float_as_uint(f);
    u += 0x7FFFu + ((u >> 16) & 1u);   // RNE
    return (unsigned short)(u >> 16);
}

// ---------------- delayed signal -> Vtg row 32 (bf16) ----------------
__global__ void k_delayed(const float* __restrict__ x,
                          const float* __restrict__ dlog,
                          unsigned short* __restrict__ Vtg) {
    int idx = blockIdx.x * blockDim.x + threadIdx.x; // over B*N
    float w[LAGS];
    float m = -1e30f;
    #pragma unroll
    for (int t = 0; t < LAGS; ++t) m = fmaxf(m, dlog[t]);
    float s = 0.f;
    #pragma unroll
    for (int t = 0; t < LAGS; ++t) { w[t] = __expf(dlog[t] - m); s += w[t]; }
    float inv = 1.f / s;
    if (idx >= Bb * Nn) return;
    int b = idx / Nn, n = idx % Nn;
    float acc = 0.f;
    #pragma unroll
    for (int t = 0; t < LAGS; ++t)
        acc += (w[t] * inv) * x[(size_t)b * Tt * Nn + (size_t)(Tt - 1 - t) * Nn + n];
    Vtg[((size_t)b * 33 + 32) * Nn + n] = f2b(acc);
}

// ---------------- fused QKV projection -> bf16 Q,K + transposed V ----------------
__global__ void k_qkv(const float* __restrict__ feat,
                      const float* __restrict__ Wq, const float* __restrict__ bq,
                      const float* __restrict__ Wk, const float* __restrict__ bk,
                      const float* __restrict__ Wv, const float* __restrict__ bv,
                      unsigned short* __restrict__ Qbf, unsigned short* __restrict__ Kbf,
                      unsigned short* __restrict__ Vtg) {
    __shared__ float WqT[Hh][Hh + 1], WkT[Hh][Hh + 1], WvT[Hh][Hh + 1];
    __shared__ float f[8][Hh];
    __shared__ __align__(16) unsigned short VT8[Hh][8];
    int tid = threadIdx.x;
    for (int i = tid; i < Hh * Hh; i += 256) {
        int h = i >> 5, k = i & 31;
        WqT[k][h] = Wq[i];
        WkT[k][h] = Wk[i];
        WvT[k][h] = Wv[i];
    }
    int n0 = blockIdx.x * 8;
    f[tid >> 5][tid & 31] = feat[(size_t)n0 * Hh + tid];
    __syncthreads();
    int lr = tid >> 5, h = tid & 31;
    float aq = bq[h], ak = bk[h], av = bv[h];
    #pragma unroll
    for (int k = 0; k < Hh; ++k) {
        float fv = f[lr][k];
        aq += fv * WqT[k][h];
        ak += fv * WkT[k][h];
        av += fv * WvT[k][h];
    }
    size_t o = (size_t)(n0 + lr) * Hh + h;
    Qbf[o] = f2b(aq);
    Kbf[o] = f2b(ak);
    VT8[h][lr] = f2b(av);
    __syncthreads();
    if (tid < 32) {
        int b = n0 >> 11, r0 = n0 & 2047;
        *(u16x8*)(Vtg + ((size_t)b * 33 + tid) * Nn + r0) = *(const u16x8*)&VT8[tid][0];
    }
}

// ---------------- MFMA flash attention (linear padded LDS, reg-staged) ----------
// 256 threads = 4 waves; wave handles 32 n-cols (2 MFMA col-tiles).
// Swapped scores: S^T[m][n] = mfma(A=K_frag, B=Q_frag). m-chunk = 128.
__global__ __launch_bounds__(256)
void k_attn(const unsigned short* __restrict__ Qbf,
            const unsigned short* __restrict__ Kbf,
            const unsigned short* __restrict__ Vtg,
            const float* __restrict__ adj,
            const float* __restrict__ geo_w,
            const float* __restrict__ feat,
            float* __restrict__ comb) {
    __shared__ __align__(16) unsigned short Kl[128 * KSTR];      // [m][k] padded
    __shared__ __align__(16) unsigned short Vl[48 * VSTR];       // [h][m] rows 0..32 staged
    __shared__ __align__(16) unsigned short Pt[4 * 32 * PSTR];   // per-wave P tile [n][m]

    int tid = threadIdx.x;
    int wid = tid >> 6, lane = tid & 63;
    int nl = lane & 15, g4 = lane >> 4;

    int bid = blockIdx.x;
    int bidl = ((bid & 7) << 5) + (bid >> 3);   // XCD-chunked swizzle (256 = 8*32)
    int b = bidl & 15;
    int ntile = bidl >> 4;                      // 0..15
    int n0w = ntile * 128 + wid * 32;

    float geo = 1.f / (1.f + __expf(-geo_w[0]));
    float cs = (1.f - geo) * 0.17677669529663687f;  // (1-geo)/sqrt(32)
    float cg = geo * 5.f;

    // Q B-fragments (col = n = lane&15, k = g4*8+j)
    s8v qf[2];
    #pragma unroll
    for (int nt = 0; nt < 2; ++nt)
        qf[nt] = *(const s8v*)(Qbf + (((size_t)b * Nn + n0w + nt * 16 + nl) << 5) + g4 * 8);

    f4 zf4 = {0.f, 0.f, 0.f, 0.f};
    f4 pacc[2][3];
    #pragma unroll
    for (int nt = 0; nt < 2; ++nt)
        #pragma unroll
        for (int t = 0; t < 3; ++t) pacc[nt][t] = zf4;
    float M[2] = {-INFINITY, -INFINITY}, S[2] = {0.f, 0.f};

    const unsigned short* Kg = Kbf + ((size_t)b * Nn * Hh);
    const unsigned short* Vg = Vtg + ((size_t)b * 33 * Nn);

    u16x8 kst[2], vst[3];
    // issue global loads for chunk c (into regs)
    auto load = [&](int c) {
        int m0 = c * 128;
        #pragma unroll
        for (int i = 0; i < 2; ++i) {
            int G = i * 256 + tid;     // 0..511: K granule (m = G>>2, gs = G&3)
            kst[i] = *(const u16x8*)(Kg + (size_t)(m0 + (G >> 2)) * 32 + (G & 3) * 8);
        }
        #pragma unroll
        for (int i = 0; i < 3; ++i) {
            int G = i * 256 + tid;     // 0..527: V granule (row = G>>4, gc = G&15)
            if (G < 528)
                vst[i] = *(const u16x8*)(Vg + (size_t)(G >> 4) * Nn + m0 + (G & 15) * 8);
        }
    };
    // write staged regs to LDS (linear padded)
    auto store = [&]() {
        #pragma unroll
        for (int i = 0; i < 2; ++i) {
            int G = i * 256 + tid;
            *(u16x8*)(Kl + (G >> 2) * KSTR + (G & 3) * 8) = kst[i];
        }
        #pragma unroll
        for (int i = 0; i < 3; ++i) {
            int G = i * 256 + tid;
            if (G < 528)
                *(u16x8*)(Vl + (G >> 4) * VSTR + (G & 15) * 8) = vst[i];
        }
    };

    load(0);
    for (int c = 0; c < Nn / 128; ++c) {
        __syncthreads();               // prev chunk's readers done
        store();                       // LDS <- chunk c
        __syncthreads();
        if (c + 1 < Nn / 128) load(c + 1);   // issue next loads early (overlap compute)
        int m0 = c * 128;
        unsigned short* Pw = Pt + wid * 32 * PSTR;

        // QK^T (swapped): per 16-m group, A = K frag (row=m), B = Q frag (col=n)
        f4 sc[8][2];
        #pragma unroll
        for (int mg = 0; mg < 8; ++mg) {
            s8v kf = *(const s8v*)(Kl + (mg * 16 + nl) * KSTR + g4 * 8);
            sc[mg][0] = __builtin_amdgcn_mfma_f32_16x16x32_bf16(kf, qf[0], zf4, 0, 0, 0);
            sc[mg][1] = __builtin_amdgcn_mfma_f32_16x16x32_bf16(kf, qf[1], zf4, 0, 0, 0);
        }

        // blend + online softmax + pack P (per n-tile)
        // sc[mg][nt][r] = S^T[m = mg*16 + g4*4 + r][n = n0w + nt*16 + nl]
        #pragma unroll
        for (int nt = 0; nt < 2; ++nt) {
            const float* arow = adj + (size_t)(n0w + nt * 16 + nl) * Nn + m0 + g4 * 4;
            #pragma unroll
            for (int mg = 0; mg < 8; ++mg) {
                f4 av = *(const f4*)(arow + mg * 16);
                sc[mg][nt][0] = cs * sc[mg][nt][0] + cg * av[0];
                sc[mg][nt][1] = cs * sc[mg][nt][1] + cg * av[1];
                sc[mg][nt][2] = cs * sc[mg][nt][2] + cg * av[2];
                sc[mg][nt][3] = cs * sc[mg][nt][3] + cg * av[3];
            }
            float cm = -INFINITY;
            #pragma unroll
            for (int mg = 0; mg < 8; ++mg) {
                f4 s = sc[mg][nt];
                cm = fmaxf(cm, fmaxf(fmaxf(s[0], s[1]), fmaxf(s[2], s[3])));
            }
            cm = fmaxf(cm, __shfl_xor(cm, 16));
            cm = fmaxf(cm, __shfl_xor(cm, 32));
            float nM = fmaxf(M[nt], cm);
            float scl = __expf(M[nt] - nM);
            M[nt] = nM;
            float ps = 0.f;
            #pragma unroll
            for (int mg = 0; mg < 8; ++mg) {
                f4 s = sc[mg][nt];
                float p0 = __expf(s[0] - nM), p1 = __expf(s[1] - nM);
                float p2 = __expf(s[2] - nM), p3 = __expf(s[3] - nM);
                ps += (p0 + p1) + (p2 + p3);
                unsigned lo = (unsigned)f2b(p0) | ((unsigned)f2b(p1) << 16);
                unsigned hi = (unsigned)f2b(p2) | ((unsigned)f2b(p3) << 16);
                // m_base = mg*16 + g4*4 within chunk; row = nt*16+nl
                *(uint2*)(Pw + (nt * 16 + nl) * PSTR + mg * 16 + g4 * 4) = make_uint2(lo, hi);
            }
            ps += __shfl_xor(ps, 16);
            ps += __shfl_xor(ps, 32);
            S[nt] = S[nt] * scl + ps;
            #pragma unroll
            for (int t = 0; t < 3; ++t) pacc[nt][t] *= scl;
        }

        // PV (+delayed-signal row 32): att^T[h][n] += V^T_frag * P^T_frag
        #pragma unroll
        for (int s4 = 0; s4 < 4; ++s4) {
            s8v pb0 = *(const s8v*)(Pw + (0 * 16 + nl) * PSTR + s4 * 32 + g4 * 8);
            s8v pb1 = *(const s8v*)(Pw + (1 * 16 + nl) * PSTR + s4 * 32 + g4 * 8);
            #pragma unroll
            for (int t = 0; t < 3; ++t) {
                s8v va = *(const s8v*)(Vl + (t * 16 + nl) * VSTR + s4 * 32 + g4 * 8);
                pacc[0][t] = __builtin_amdgcn_mfma_f32_16x16x32_bf16(va, pb0, pacc[0][t], 0, 0, 0);
                pacc[1][t] = __builtin_amdgcn_mfma_f32_16x16x32_bf16(va, pb1, pacc[1][t], 0, 0, 0);
            }
        }
    }

    // epilogue: comb = feat + attended + 0.1*prop
    // pacc[nt][t][r] = att^T[h = t*16 + g4*4 + r][n = n0w + nt*16 + nl]
    #pragma unroll
    for (int nt = 0; nt < 2; ++nt) {
        float invS = 1.f / S[nt];
        float pp = __shfl(pacc[nt][2][0], nl) * invS * 0.1f;  // h=32 lives on g4==0,reg0
        size_t o = ((size_t)b * Nn + n0w + nt * 16 + nl) * Hh;
        #pragma unroll
        for (int t = 0; t < 2; ++t) {
            f4 fv = *(const f4*)(feat + o + t * 16 + g4 * 4);
            f4 ov = fv + pacc[nt][t] * invS;
            ov[0] += pp; ov[1] += pp; ov[2] += pp; ov[3] += pp;
            *(f4*)(comb + o + t * 16 + g4 * 4) = ov;
        }
    }
}

// ---------------- output projection + LayerNorm ----------------
__global__ void k_projln(const float* __restrict__ comb,
                         const float* __restrict__ Wo, const float* __restrict__ bo,
                         const float* __restrict__ gamma, const float* __restrict__ beta,
                         float* __restrict__ out) {
    __shared__ float WoT[Hh][Hh + 1];
    __shared__ float f[8][Hh];
    int tid = threadIdx.x;
    for (int i = tid; i < Hh * Hh; i += 256) {
        WoT[i & 31][i >> 5] = Wo[i];
    }
    int row0 = blockIdx.x * 8;
    f[tid >> 5][tid & 31] = comb[(size_t)row0 * Hh + tid];
    __syncthreads();
    int lr = tid >> 5, h = tid & 31;
    float a = bo[h];
    #pragma unroll
    for (int k = 0; k < Hh; ++k) a += f[lr][k] * WoT[k][h];
    float mu = a;
    #pragma unroll
    for (int w = 1; w < 32; w <<= 1) mu += __shfl_xor(mu, w);
    mu *= (1.f / 32.f);
    float d = a - mu;
    float v = d * d;
    #pragma unroll
    for (int w = 1; w < 32; w <<= 1) v += __shfl_xor(v, w);
    v *= (1.f / 32.f);
    out[(size_t)row0 * Hh + tid] = d * rsqrtf(v + LN_EPS) * gamma[h] + beta[h];
}

extern "C" void kernel_launch(void* const* d_in, const int* in_sizes, int n_in,
                              void* d_out, int out_size, void* d_ws, size_t ws_size,
                              hipStream_t stream) {
    const float* x     = (const float*)d_in[0];
    const float* feat  = (const float*)d_in[1];
    const float* dlog  = (const float*)d_in[2];
    const float* Wq    = (const float*)d_in[3];
    const float* bq    = (const float*)d_in[4];
    const float* Wk    = (const float*)d_in[5];
    const float* bk    = (const float*)d_in[6];
    const float* Wv    = (const float*)d_in[7];
    const float* bv    = (const float*)d_in[8];
    const float* adj   = (const float*)d_in[9];
    const float* geo   = (const float*)d_in[10];
    const float* Wo    = (const float*)d_in[11];
    const float* bo    = (const float*)d_in[12];
    const float* gamma = (const float*)d_in[13];
    const float* beta  = (const float*)d_in[14];
    float* out = (float*)d_out;

    char* w = (char*)d_ws;
    unsigned short* Qbf = (unsigned short*)w;  w += (size_t)Bb * Nn * Hh * 2;
    unsigned short* Kbf = (unsigned short*)w;  w += (size_t)Bb * Nn * Hh * 2;
    unsigned short* Vtg = (unsigned short*)w;  w += (size_t)Bb * 33 * Nn * 2;
    float* comb = (float*)w;

    k_delayed<<<(Bb * Nn + 255) / 256, 256, 0, stream>>>(x, dlog, Vtg);
    k_qkv<<<Bb * Nn / 8, 256, 0, stream>>>(feat, Wq, bq, Wk, bk, Wv, bv, Qbf, Kbf, Vtg);
    k_attn<<<256, 256, 0, stream>>>(Qbf, Kbf, Vtg, adj, geo, feat, comb);
    k_projln<<<Bb * Nn / 8, 256, 0, stream>>>(comb, Wo, bo, gamma, beta, out);
}